// Round 8
// baseline (36.546 us; speedup 1.0000x reference)
//
#include <hip/hip_runtime.h>

// MIL loss: per-batch masked max over H*W, then mean BCE-with-logits over B.
// B=128, H=W=512, zones int32 in [0,50), cats int32 in [0,50), labels {0,1}.
//
// Memory-bound-ish: must stream all of zones (134 MB); logits fetched only
// where a 64B line has a zone==cat hit (~27.6% of lines). Touched ~168 MB.
// R6 A/B (temporal vs nontemporal neutral) => issue/latency-limited, not HBM
// BW-limited. This round: decoupled chunked compare->gather to raise per-wave
// outstanding VMEM (4 z-loads + 4 independent l-loads per chunk, depth-2
// chunk prefetch), VGPRs kept <=64 for full 32 waves/CU occupancy.

typedef int   i32x4 __attribute__((ext_vector_type(4)));
typedef float f32x4 __attribute__((ext_vector_type(4)));

constexpr int B   = 128;
constexpr int HW  = 512 * 512;          // 262144 pixels per batch
constexpr int TPB = 256;                // threads per block
constexpr int BPB = 16;                 // blocks/batch -> grid 2048 = 8 blocks/CU, one round
constexpr int V4_PER_BATCH = HW / 4;    // 65536 vec4 per batch
constexpr int VPT = V4_PER_BATCH / (TPB * BPB);  // = 16 vec4 per thread
constexpr int CH  = 4;                  // vec4 per chunk (32 VGPR of z-storage w/ prefetch)
constexpr int NCH = VPT / CH;           // 4 chunks
constexpr float NEG = -1e30f;

__global__ __launch_bounds__(TPB) void mil_stage1(
    const float* __restrict__ logits,
    const int*   __restrict__ zones,
    const int*   __restrict__ cats,
    float* __restrict__ pmax,
    int*   __restrict__ pany)
{
    const int b   = blockIdx.x / BPB;
    const int blk = blockIdx.x % BPB;
    const int cat = cats[b];            // uniform across block

    float m   = NEG;
    int   any = 0;

    if (cat > 0) {                      // cat<=0 => mask identically false for the batch
        const i32x4* z4 = reinterpret_cast<const i32x4*>(zones)
                        + (size_t)b * V4_PER_BATCH + (size_t)blk * (TPB * VPT) + threadIdx.x;
        const f32x4* l4 = reinterpret_cast<const f32x4*>(logits)
                        + (size_t)b * V4_PER_BATCH + (size_t)blk * (TPB * VPT) + threadIdx.x;

        // prologue: chunk 0's z-loads in flight
        i32x4 za[CH];
#pragma unroll
        for (int j = 0; j < CH; ++j) za[j] = z4[j * TPB];

#pragma unroll
        for (int c = 0; c < NCH; ++c) {
            // depth-2: issue next chunk's z-loads before consuming this chunk
            i32x4 zb[CH];
            if (c + 1 < NCH) {
#pragma unroll
                for (int j = 0; j < CH; ++j) zb[j] = z4[((c + 1) * CH + j) * TPB];
            }

            // branchless 16-bit hit mask for this chunk (cat>0 uniform-true,
            // so z==cat implies z>0)
            unsigned hm = 0u;
#pragma unroll
            for (int j = 0; j < CH; ++j) {
                hm |= (za[j].x == cat ? (1u << (4 * j + 0)) : 0u);
                hm |= (za[j].y == cat ? (1u << (4 * j + 1)) : 0u);
                hm |= (za[j].z == cat ? (1u << (4 * j + 2)) : 0u);
                hm |= (za[j].w == cat ? (1u << (4 * j + 3)) : 0u);
            }
            any |= (hm != 0u);

            // gather phase: the chunk's l-loads are mutually independent —
            // no z-compare interleaved between their issues
#pragma unroll
            for (int j = 0; j < CH; ++j) {
                const unsigned sm = (hm >> (4 * j)) & 0xFu;
                if (sm) {
                    const f32x4 v = l4[(c * CH + j) * TPB];
                    if (sm & 1u) m = fmaxf(m, v.x);
                    if (sm & 2u) m = fmaxf(m, v.y);
                    if (sm & 4u) m = fmaxf(m, v.z);
                    if (sm & 8u) m = fmaxf(m, v.w);
                }
            }

#pragma unroll
            for (int j = 0; j < CH; ++j) za[j] = zb[j];
        }
    }

    // wave (64-lane) down reduction
#pragma unroll
    for (int off = 32; off > 0; off >>= 1) {
        m   = fmaxf(m, __shfl_down(m, off, 64));
        any |= __shfl_down(any, off, 64);
    }

    __shared__ float sm_[TPB / 64];
    __shared__ int   sa_[TPB / 64];
    const int lane = threadIdx.x & 63;
    const int wid  = threadIdx.x >> 6;
    if (lane == 0) { sm_[wid] = m; sa_[wid] = any; }
    __syncthreads();
    if (threadIdx.x == 0) {
        float mm = sm_[0];
        int   aa = sa_[0];
#pragma unroll
        for (int w = 1; w < TPB / 64; ++w) { mm = fmaxf(mm, sm_[w]); aa |= sa_[w]; }
        pmax[b * BPB + blk] = mm;
        pany[b * BPB + blk] = aa;
    }
}

__global__ __launch_bounds__(128) void mil_stage2(
    const float* __restrict__ pmax,
    const int*   __restrict__ pany,
    const int*   __restrict__ labels,
    float* __restrict__ out)
{
    const int b = threadIdx.x;          // 0..127, one thread per batch
    float mm = NEG;
    int   aa = 0;
#pragma unroll
    for (int k = 0; k < BPB; ++k) {
        mm = fmaxf(mm, pmax[b * BPB + k]);
        aa |= pany[b * BPB + k];
    }
    const float s = aa ? mm : 0.0f;
    const float y = (float)labels[b];
    float loss = fmaxf(s, 0.0f) - s * y + log1pf(expf(-fabsf(s)));

    // sum-reduce 128 threads (2 waves)
#pragma unroll
    for (int off = 32; off > 0; off >>= 1)
        loss += __shfl_down(loss, off, 64);

    __shared__ float ss[2];
    const int lane = threadIdx.x & 63;
    const int wid  = threadIdx.x >> 6;
    if (lane == 0) ss[wid] = loss;
    __syncthreads();
    if (threadIdx.x == 0) out[0] = (ss[0] + ss[1]) / (float)B;
}

extern "C" void kernel_launch(void* const* d_in, const int* in_sizes, int n_in,
                              void* d_out, int out_size, void* d_ws, size_t ws_size,
                              hipStream_t stream)
{
    const float* logits = (const float*)d_in[0];   // (B,1,H,W) f32
    const int*   zones  = (const int*)  d_in[1];   // (B,H,W)  i32
    const int*   cats   = (const int*)  d_in[2];   // (B,)     i32
    const int*   labels = (const int*)  d_in[3];   // (B,)     i32
    float*       out    = (float*)d_out;

    float* pmax = (float*)d_ws;                              // B*BPB floats
    int*   pany = (int*)((char*)d_ws + B * BPB * sizeof(float));

    mil_stage1<<<B * BPB, TPB, 0, stream>>>(logits, zones, cats, pmax, pany);
    mil_stage2<<<1, 128, 0, stream>>>(pmax, pany, labels, out);
}